// Round 2
// baseline (1599.684 us; speedup 1.0000x reference)
//
#include <hip/hip_runtime.h>
#include <hip/hip_bf16.h>
#include <cmath>

typedef __attribute__((ext_vector_type(8))) short bf16x8;
typedef __attribute__((ext_vector_type(4))) float f32x4;
typedef unsigned short u16;

#define HSIZE (1u << 19)
#define N_POINTS 524288
#define BM 128

struct HashMeta { int R[16]; unsigned off[16]; };

static __device__ __forceinline__ u16 f2bf(float f) {
    unsigned u = __float_as_uint(f);
    return (u16)((u + 0x7FFFu + ((u >> 16) & 1u)) >> 16);
}

// ---------------- weight prep: W = v * (g / ||v||_row), bf16, padded layouts ----------------
// W0b: [256][64]  (K padded 35->64 with zeros)
// W1b: [256][256]
// W2b: [272][256] (row n<256 = v2 row n+1; row 256 = v2 row 0 (sdf); rows 257..271 zero)
__global__ __launch_bounds__(64) void prep_weights(
    const float* __restrict__ v0, const float* __restrict__ g0,
    const float* __restrict__ v1, const float* __restrict__ g1,
    const float* __restrict__ v2, const float* __restrict__ g2,
    u16* __restrict__ W0b, u16* __restrict__ W1b, u16* __restrict__ W2b)
{
    const int b = blockIdx.x;
    const int lane = threadIdx.x;
    if (b < 256) {
        float val = (lane < 35) ? v0[b * 35 + lane] : 0.f;
        float s = val * val;
        for (int o = 32; o; o >>= 1) s += __shfl_down(s, o);
        float norm = __shfl(sqrtf(s), 0);
        float sc = g0[b] / norm;
        W0b[b * 64 + lane] = f2bf(val * sc);
    } else if (b < 512) {
        const int r = b - 256;
        float v[4]; float s = 0.f;
        for (int j = 0; j < 4; ++j) { v[j] = v1[r * 256 + lane + 64 * j]; s += v[j] * v[j]; }
        for (int o = 32; o; o >>= 1) s += __shfl_down(s, o);
        float norm = __shfl(sqrtf(s), 0);
        float sc = g1[r] / norm;
        for (int j = 0; j < 4; ++j) W1b[r * 256 + lane + 64 * j] = f2bf(v[j] * sc);
    } else if (b < 769) {
        const int r = b - 512;                 // 0..256 : source row of v2
        float v[4]; float s = 0.f;
        for (int j = 0; j < 4; ++j) { v[j] = v2[r * 256 + lane + 64 * j]; s += v[j] * v[j]; }
        for (int o = 32; o; o >>= 1) s += __shfl_down(s, o);
        float norm = __shfl(sqrtf(s), 0);
        float sc = g2[r] / norm;
        const int dr = (r == 0) ? 256 : (r - 1);
        for (int j = 0; j < 4; ++j) W2b[dr * 256 + lane + 64 * j] = f2bf(v[j] * sc);
    } else {
        // zero pad rows 257..271 of W2b
        for (int i = lane; i < 15 * 256; i += 64) W2b[257 * 256 + i] = 0;
    }
}

// ---------------- fused: encode -> L0(softplus) -> L1(softplus) -> L2 -> out ----------------
// LDS: h0 [128][64] bf16 (16 KB) + h1 [128][256] bf16 (64 KB) = 80 KB.
// GEMM2 writes its output IN PLACE into h1 (K-loop fully consumes h1 into
// registers, barrier, epilogue overwrites, barrier).
__global__ __launch_bounds__(512) void fused_mlp(
    const float* __restrict__ x, const float* __restrict__ table,
    const u16* __restrict__ W0b, const float* __restrict__ b0,
    const u16* __restrict__ W1b, const float* __restrict__ b1,
    const u16* __restrict__ W2b, const float* __restrict__ b2,
    float* __restrict__ out, HashMeta meta)
{
    __shared__ u16 h0[BM * 64];     // [row][64] swizzled; cols 0-2 x, 3-34 feats, 35-63 zero
    __shared__ u16 h1[BM * 256];    // [row][256] swizzled

    const int tid = threadIdx.x;
    const int p0 = blockIdx.x * BM;

    // zero h0 (covers K padding)
    {
        int* z = (int*)h0;
        for (int i = tid; i < BM * 32; i += 512) z[i] = 0;
    }
    __syncthreads();

    // ---- hash-grid encode: 4 threads/point, 4 levels each ----
    {
        const int m = tid >> 2;          // point within tile
        const int sub = tid & 3;
        const int p = p0 + m;
        float xr[3], x01[3];
        #pragma unroll
        for (int c = 0; c < 3; ++c) {
            xr[c] = x[p * 3 + c];
            float v = (xr[c] / 1.5f + 1.f) * 0.5f;
            x01[c] = fminf(fmaxf(v, 0.f), 1.f);
        }
        if (sub == 0) {
            #pragma unroll
            for (int c = 0; c < 3; ++c)
                h0[m * 64 + (c ^ ((m & 7) << 3))] = f2bf(xr[c]);
        }
        const float2* tab2 = (const float2*)table;
        for (int li = 0; li < 4; ++li) {
            const int l = sub * 4 + li;
            const int R = meta.R[l];
            const unsigned off = meta.off[l];
            const unsigned S = (unsigned)(R + 1);
            const bool hashed = ((long long)S * S * S) > (long long)HSIZE;
            float fr[3]; unsigned i0[3];
            #pragma unroll
            for (int c = 0; c < 3; ++c) {
                float pos = x01[c] * (float)(R - 1);
                float f0 = floorf(pos);
                f0 = fminf(fmaxf(f0, 0.f), (float)(R - 2));
                fr[c] = pos - f0;
                i0[c] = (unsigned)f0;
            }
            float f0a = 0.f, f1a = 0.f;
            #pragma unroll
            for (int c = 0; c < 8; ++c) {
                unsigned cx = i0[0] + (c & 1), cy = i0[1] + ((c >> 1) & 1), cz = i0[2] + ((c >> 2) & 1);
                float w = ((c & 1) ? fr[0] : 1.f - fr[0])
                        * ((c & 2) ? fr[1] : 1.f - fr[1])
                        * ((c & 4) ? fr[2] : 1.f - fr[2]);
                unsigned idx_h = (cx ^ (cy * 2654435761u) ^ (cz * 805459861u)) & (HSIZE - 1u);
                unsigned idx_g = cx + cy * S + cz * S * S;
                unsigned idx = hashed ? idx_h : idx_g;
                float2 tv = tab2[idx + off];
                f0a += w * tv.x;
                f1a += w * tv.y;
            }
            const int cb = 3 + 2 * l;
            h0[m * 64 + (cb       ^ ((m & 7) << 3))] = f2bf(f0a);
            h0[m * 64 + ((cb + 1) ^ ((m & 7) << 3))] = f2bf(f1a);
        }
    }
    __syncthreads();

    const int lane = tid & 63;
    const int wid = tid >> 6;    // 0..7
    const int wr = wid >> 2;     // 0..1  (row half, 64 rows)
    const int wc = wid & 3;      // 0..3  (col quarter, 64 cols)
    const int l15 = lane & 15;
    const int lq = lane >> 4;    // 0..3

    // ---- GEMM1: [128 x 64pad] @ W0b^T -> softplus -> h1 [128 x 256] ----
    {
        f32x4 acc[4][4];
        #pragma unroll
        for (int i = 0; i < 4; ++i)
            #pragma unroll
            for (int j = 0; j < 4; ++j) acc[i][j] = 0.f;
        #pragma unroll
        for (int ks = 0; ks < 2; ++ks) {
            const int kb = ks * 32 + lq * 8;
            bf16x8 a[4], b[4];
            #pragma unroll
            for (int mi = 0; mi < 4; ++mi) {
                const int r = wr * 64 + mi * 16 + l15;
                a[mi] = *reinterpret_cast<const bf16x8*>(&h0[r * 64 + (kb ^ ((r & 7) << 3))]);
            }
            #pragma unroll
            for (int ni = 0; ni < 4; ++ni) {
                const int n = wc * 64 + ni * 16 + l15;
                b[ni] = *reinterpret_cast<const bf16x8*>(&W0b[n * 64 + kb]);
            }
            #pragma unroll
            for (int mi = 0; mi < 4; ++mi)
                #pragma unroll
                for (int ni = 0; ni < 4; ++ni)
                    acc[mi][ni] = __builtin_amdgcn_mfma_f32_16x16x32_bf16(a[mi], b[ni], acc[mi][ni], 0, 0, 0);
        }
        #pragma unroll
        for (int mi = 0; mi < 4; ++mi)
            #pragma unroll
            for (int ni = 0; ni < 4; ++ni) {
                const int n = wc * 64 + ni * 16 + l15;
                const float bias = b0[n];
                #pragma unroll
                for (int j = 0; j < 4; ++j) {
                    const int r = wr * 64 + mi * 16 + lq * 4 + j;
                    float t = (acc[mi][ni][j] + bias) * 100.f;
                    float sp = (fmaxf(t, 0.f) + __logf(1.f + __expf(-fabsf(t)))) * 0.01f;
                    h1[r * 256 + (n ^ ((r & 7) << 3))] = f2bf(sp);
                }
            }
    }
    __syncthreads();

    // ---- GEMM2: h1 @ W1b^T -> softplus -> h1 (IN PLACE) ----
    {
        f32x4 acc[4][4];
        #pragma unroll
        for (int i = 0; i < 4; ++i)
            #pragma unroll
            for (int j = 0; j < 4; ++j) acc[i][j] = 0.f;
        #pragma unroll
        for (int ks = 0; ks < 8; ++ks) {
            const int kb = ks * 32 + lq * 8;
            bf16x8 a[4], b[4];
            #pragma unroll
            for (int mi = 0; mi < 4; ++mi) {
                const int r = wr * 64 + mi * 16 + l15;
                a[mi] = *reinterpret_cast<const bf16x8*>(&h1[r * 256 + (kb ^ ((r & 7) << 3))]);
            }
            #pragma unroll
            for (int ni = 0; ni < 4; ++ni) {
                const int n = wc * 64 + ni * 16 + l15;
                b[ni] = *reinterpret_cast<const bf16x8*>(&W1b[n * 256 + kb]);
            }
            #pragma unroll
            for (int mi = 0; mi < 4; ++mi)
                #pragma unroll
                for (int ni = 0; ni < 4; ++ni)
                    acc[mi][ni] = __builtin_amdgcn_mfma_f32_16x16x32_bf16(a[mi], b[ni], acc[mi][ni], 0, 0, 0);
        }
        // all reads of h1 are complete (acc in registers) -> safe to overwrite
        __syncthreads();
        #pragma unroll
        for (int mi = 0; mi < 4; ++mi)
            #pragma unroll
            for (int ni = 0; ni < 4; ++ni) {
                const int n = wc * 64 + ni * 16 + l15;
                const float bias = b1[n];
                #pragma unroll
                for (int j = 0; j < 4; ++j) {
                    const int r = wr * 64 + mi * 16 + lq * 4 + j;
                    float t = (acc[mi][ni][j] + bias) * 100.f;
                    float sp = (fmaxf(t, 0.f) + __logf(1.f + __expf(-fabsf(t)))) * 0.01f;
                    h1[r * 256 + (n ^ ((r & 7) << 3))] = f2bf(sp);
                }
            }
    }
    __syncthreads();

    // ---- GEMM3: h1 @ W2b^T -> out ----
    // main: cols n in 0..255 -> outcol n+1.  sdf: W2b row 256 -> outcol 0,
    // handled as one extra 16x16 tile per wave (wave wid owns rows wid*16..+16).
    {
        f32x4 acc[4][4];
        #pragma unroll
        for (int i = 0; i < 4; ++i)
            #pragma unroll
            for (int j = 0; j < 4; ++j) acc[i][j] = 0.f;
        #pragma unroll
        for (int ks = 0; ks < 8; ++ks) {
            const int kb = ks * 32 + lq * 8;
            bf16x8 a[4], b[4];
            #pragma unroll
            for (int mi = 0; mi < 4; ++mi) {
                const int r = wr * 64 + mi * 16 + l15;
                a[mi] = *reinterpret_cast<const bf16x8*>(&h1[r * 256 + (kb ^ ((r & 7) << 3))]);
            }
            #pragma unroll
            for (int ni = 0; ni < 4; ++ni) {
                const int n = wc * 64 + ni * 16 + l15;
                b[ni] = *reinterpret_cast<const bf16x8*>(&W2b[n * 256 + kb]);
            }
            #pragma unroll
            for (int mi = 0; mi < 4; ++mi)
                #pragma unroll
                for (int ni = 0; ni < 4; ++ni)
                    acc[mi][ni] = __builtin_amdgcn_mfma_f32_16x16x32_bf16(a[mi], b[ni], acc[mi][ni], 0, 0, 0);
        }
        #pragma unroll
        for (int mi = 0; mi < 4; ++mi)
            #pragma unroll
            for (int ni = 0; ni < 4; ++ni) {
                const int n = wc * 64 + ni * 16 + l15;
                const float bias = b2[n + 1];
                #pragma unroll
                for (int j = 0; j < 4; ++j) {
                    const int r = wr * 64 + mi * 16 + lq * 4 + j;
                    __builtin_nontemporal_store(acc[mi][ni][j] + bias,
                                                &out[(long)(p0 + r) * 257 + (n + 1)]);
                }
            }

        // sdf tile: rows wid*16..wid*16+16, weight rows 256..271 (257..271 zero)
        f32x4 accS;
        #pragma unroll
        for (int j = 0; j < 4; ++j) accS[j] = 0.f;
        #pragma unroll
        for (int ks = 0; ks < 8; ++ks) {
            const int kb = ks * 32 + lq * 8;
            const int r = wid * 16 + l15;
            bf16x8 a = *reinterpret_cast<const bf16x8*>(&h1[r * 256 + (kb ^ ((r & 7) << 3))]);
            bf16x8 b = *reinterpret_cast<const bf16x8*>(&W2b[(256 + l15) * 256 + kb]);
            accS = __builtin_amdgcn_mfma_f32_16x16x32_bf16(a, b, accS, 0, 0, 0);
        }
        if (l15 == 0) {
            const float bias = b2[0];
            #pragma unroll
            for (int j = 0; j < 4; ++j) {
                const int r = wid * 16 + lq * 4 + j;
                __builtin_nontemporal_store(accS[j] + bias, &out[(long)(p0 + r) * 257]);
            }
        }
    }
}

extern "C" void kernel_launch(void* const* d_in, const int* in_sizes, int n_in,
                              void* d_out, int out_size, void* d_ws, size_t ws_size,
                              hipStream_t stream)
{
    (void)in_sizes; (void)n_in; (void)out_size; (void)ws_size;
    const float* x     = (const float*)d_in[0];
    const float* table = (const float*)d_in[1];
    const float* v0 = (const float*)d_in[2];
    const float* g0 = (const float*)d_in[3];
    const float* b0 = (const float*)d_in[4];
    const float* v1 = (const float*)d_in[5];
    const float* g1 = (const float*)d_in[6];
    const float* b1 = (const float*)d_in[7];
    const float* v2 = (const float*)d_in[8];
    const float* g2 = (const float*)d_in[9];
    const float* b2 = (const float*)d_in[10];
    float* out = (float*)d_out;

    u16* W0b = (u16*)d_ws;                          // 32768 B
    u16* W1b = (u16*)((char*)d_ws + 32768);         // 131072 B
    u16* W2b = (u16*)((char*)d_ws + 163840);        // 139264 B  (total 303104 B)

    HashMeta meta;
    {
        const double scale = pow(2.0, log2(2048.0 / 16.0) / 15.0);
        unsigned off = 0;
        for (int i = 0; i < 16; ++i) {
            long long R = (long long)ceil(16.0 * pow(scale, (double)i));
            meta.R[i] = (int)R;
            meta.off[i] = off;
            long long S3 = (R + 1) * (R + 1) * (R + 1);
            long long n = S3 < (long long)HSIZE ? S3 : (long long)HSIZE;
            n = (n + 7) / 8 * 8;
            off += (unsigned)n;
        }
    }

    prep_weights<<<770, 64, 0, stream>>>(v0, g0, v1, g1, v2, g2, W0b, W1b, W2b);
    fused_mlp<<<N_POINTS / BM, 512, 0, stream>>>(x, table, W0b, b0, W1b, b1, W2b, b2, out, meta);
}